// Round 3
// baseline (81.807 us; speedup 1.0000x reference)
//
#include <hip/hip_runtime.h>
#include <hip/hip_bf16.h>

// AssignIndex: out = arr, except out[index, :] = element.
// arr: [65536, 1024] f32 (256 MiB), element: [1024] f32, index: device scalar int.
// Memory-bound copy. One-shot grid, 8 float4 per thread (MLP=8) issued
// back-to-back, nontemporal stores so the write stream doesn't evict arr
// from L2/L3 (harness fills trash L3 anyway; reads stay cached-hinted).

typedef float floatx4 __attribute__((ext_vector_type(4)));

#define D4 256          // 1024 floats / 4 per float4; row = i4 >> 8
#define PER_THREAD 8
#define BLOCK 256

__global__ __launch_bounds__(BLOCK) void assign_index_kernel(
    const floatx4* __restrict__ arr,
    const int* __restrict__ index_p,
    const floatx4* __restrict__ elem,
    floatx4* __restrict__ out,
    long long n4)
{
    const int index = *index_p;  // uniform scalar load
    const long long base = (long long)blockIdx.x * (BLOCK * PER_THREAD) + threadIdx.x;

    if (base + (PER_THREAD - 1) * BLOCK < n4) {
        // fast path: 8 outstanding loads, then 8 nt stores
        floatx4 v[PER_THREAD];
#pragma unroll
        for (int k = 0; k < PER_THREAD; ++k)
            v[k] = arr[base + k * BLOCK];
#pragma unroll
        for (int k = 0; k < PER_THREAD; ++k) {
            long long i = base + k * BLOCK;
            if ((int)(i >> 8) == index)
                v[k] = elem[i & (D4 - 1)];
            __builtin_nontemporal_store(v[k], &out[i]);
        }
    } else {
#pragma unroll
        for (int k = 0; k < PER_THREAD; ++k) {
            long long i = base + k * BLOCK;
            if (i < n4) {
                floatx4 v = arr[i];
                if ((int)(i >> 8) == index)
                    v = elem[i & (D4 - 1)];
                __builtin_nontemporal_store(v, &out[i]);
            }
        }
    }
}

extern "C" void kernel_launch(void* const* d_in, const int* in_sizes, int n_in,
                              void* d_out, int out_size, void* d_ws, size_t ws_size,
                              hipStream_t stream) {
    const floatx4* arr  = (const floatx4*)d_in[0];
    const int*     idx  = (const int*)d_in[1];
    const floatx4* elem = (const floatx4*)d_in[2];
    floatx4* out = (floatx4*)d_out;

    const long long n4 = (long long)out_size / 4;  // 16,777,216
    const long long per_block = BLOCK * PER_THREAD; // 2048 float4 per block
    const int grid = (int)((n4 + per_block - 1) / per_block);  // 8192

    assign_index_kernel<<<grid, BLOCK, 0, stream>>>(arr, idx, elem, out, n4);
}